// Round 5
// baseline (252.178 us; speedup 1.0000x reference)
//
#include <hip/hip_runtime.h>
#include <hip/hip_cooperative_groups.h>

namespace cg = cooperative_groups;

// Problem sizes (fixed by the reference)
constexpr int kB    = 2048;  // batch
constexpr int kVIS  = 2048;  // visible units (GEMM K)
constexpr int kHID  = 1024;  // hidden units (GEMM N)
constexpr int kCLS  = 64;    // classes
constexpr float kLog2e = 1.4426950408889634f;

typedef __attribute__((ext_vector_type(8))) short bf16x8;
typedef __attribute__((ext_vector_type(4))) float f32x4;
typedef __attribute__((ext_vector_type(2))) float f32x2;

typedef __attribute__((address_space(3))) unsigned       as3_u32;
typedef __attribute__((address_space(1))) const unsigned as1_u32;

__device__ __forceinline__ void g2lds16(const void* g, void* l) {
    // async global->LDS DMA, 16 B per lane; LDS dest is wave-base + lane*16
    __builtin_amdgcn_global_load_lds((as1_u32*)g, (as3_u32*)l, 16, 0, 0);
}

__device__ __forceinline__ unsigned short f2bf(float x) {
    unsigned u = __float_as_uint(x);
    u += 0x7fffu + ((u >> 16) & 1u);
    return (unsigned short)(u >> 16);
}
__device__ __forceinline__ float bf2f(unsigned short h) {
    return __uint_as_float(((unsigned)h) << 16);
}

// ================== R14: single cooperative kernel — prep | gemm | softmax ==============
// R4 accounting: gemm 51.3 us but total 130 us; prep+softmax are ~15 us by traffic
// arithmetic -> ~60 us of the total is inter-kernel gaps + launch overhead. Fusing all
// three phases into one cooperative launch (512 blocks x 512 thr = exactly the 2/CU
// co-residency our 64 KB LDS already forces) removes 2 launch gaps and runs prep at
// full-chip parallelism. grid.sync() provides the device-scope fencing the phase
// handoffs need (vh/wth written in phase 1, DMA-read in phase 2; Fpart in 2 -> 3).
// Phase 2 is the round-0 proven gemm body VERBATIM (51.2-51.4 us, 3 rounds stable).
__global__ __launch_bounds__(512, 4) void fused_all(const float* __restrict__ v,
                                                    const float* __restrict__ W,
                                                    const float* __restrict__ U,
                                                    const float* __restrict__ cvec,
                                                    const float* __restrict__ dvec,
                                                    unsigned short* __restrict__ vh,
                                                    unsigned short* __restrict__ vl,
                                                    unsigned short* __restrict__ wth,
                                                    unsigned short* __restrict__ wtl,
                                                    float* __restrict__ Utp,
                                                    float* __restrict__ Fpart,
                                                    float* __restrict__ out) {
    __shared__ __align__(16) union SMem {
        unsigned short stage[2][4][64 * 64];  // [buf][Ah,Al,Bh,Bl][row][k]  = 65536 B
        float psH[2][64][68];                 // 34816 B, overlays stage
        float T[64][65];                      // 16640 B, prep transpose tile
    } smem;

    const int tid = threadIdx.x;
    const int bid = blockIdx.x;
    const int lane = tid & 63, wave = tid >> 6;   // wave 0..7

    // ---------------- phase 1a: v split, grid-strided (1,048,576 float4 / 262,144 thr)
    {
        const int gthr = bid * 512 + tid;
#pragma unroll
        for (int it = 0; it < 4; ++it) {
            const int i = (gthr + it * 262144) * 4;
            const float4 xv = *(const float4*)(v + i);
            ushort4 h, l;
            h.x = f2bf(xv.x); l.x = f2bf(xv.x - bf2f(h.x));
            h.y = f2bf(xv.y); l.y = f2bf(xv.y - bf2f(h.y));
            h.z = f2bf(xv.z); l.z = f2bf(xv.z - bf2f(h.z));
            h.w = f2bf(xv.w); l.w = f2bf(xv.w - bf2f(h.w));
            *(ushort4*)(vh + i) = h;
            *(ushort4*)(vl + i) = l;
        }
    }
    // ---------------- phase 1b: W split+transpose, one 64x64 tile per block
    {
        const int n0 = (bid & 15) * 64;          // 16 n-tiles
        const int k0 = (bid >> 4) * 64;          // 32 k-tiles
        const int c = lane, r0 = wave;           // 8 waves x 8 passes = 64 rows
#pragma unroll
        for (int ps = 0; ps < 8; ++ps) {
            const int r = r0 + ps * 8;
            smem.T[r][c] = W[(size_t)(k0 + r) * kHID + n0 + c];   // 256 B/wave
        }
        __syncthreads();
#pragma unroll
        for (int ps = 0; ps < 8; ++ps) {
            const int nn = r0 + ps * 8;
            const float x = smem.T[c][nn];       // (c+nn)%32 banks, 2-way alias: free
            const unsigned short h = f2bf(x);
            const unsigned short l = f2bf(x - bf2f(h));
            const size_t o = (size_t)(n0 + nn) * kVIS + k0 + c;
            wth[o] = h;                          // 128 B/wave, coalesced
            wtl[o] = l;
        }
    }
    // ---------------- phase 1c: U pack+scale, 128 elems per block
    if (tid < 128) {
        const int id = bid * 128 + tid;          // 0..65535
        const int j = id >> 6, y = id & 63;
        Utp[(((j >> 2) * kCLS + y) << 2) + (j & 3)] = U[(size_t)y * kHID + j] * kLog2e;
    }

    cg::this_grid().sync();   // prep results visible device-wide; T dead, stage live

    // ---------------- phase 2: gemm + softplus partial-F (round-0 body, verbatim) -----
    const int mh = wave >> 2;                     // m-half: rows mh*32..+32
    const int nh = (wave >> 1) & 1;               // n-half: cols nh*32..+32
    const int kh = wave & 1;                      // k-half: k in [kh*32,+32) of each slab

    // XCD-aware decomposition of the 1D grid (512 blocks, 32 m-stripes x 16 n-tiles)
    const int idx = bid >> 3;                           // 0..63
    const int mstripe = ((bid & 7) << 2) + (idx >> 4);  // 0..31
    const int ncol = idx & 15;                          // 0..15
    const int m0 = mstripe * 64, n0 = ncol * 64;

    // staging: 512 threads x 16 B = one 8 KB array per DMA set; thread covers one row-slot
    const int r = tid >> 3;                                 // 0..63
    const int oc = (((tid & 7) ^ ((tid >> 3) & 7)) << 3);   // global k-octet (XOR swizzle)
    const size_t ga = (size_t)(m0 + r) * kVIS + oc;
    const size_t gb = (size_t)(n0 + r) * kVIS + oc;
    const int ls = (r << 6) + ((tid & 7) << 3);             // physical LDS slot (elems)

    // fragment addressing: frag[row][k], row-major LDK=64, swizzled octet.
    const int fm = lane & 15, fq = lane >> 4;
    const int rx = fm & 7;
    const int ar0 = (mh * 32 + fm) << 6, ar1 = (mh * 32 + 16 + fm) << 6;
    const int br0 = (nh * 32 + fm) << 6, br1 = (nh * 32 + 16 + fm) << 6;
    const int p = (((kh << 2) + fq) ^ rx) << 3;             // swizzled octet for this wave

    f32x4 acc[2][2] = {};   // [m-tile][n-tile], 16 VGPRs

    // prime: DMA slab 0 into buffer 0
    {
        g2lds16(vh + ga,  smem.stage[0][0] + ls);
        g2lds16(vl + ga,  smem.stage[0][1] + ls);
        g2lds16(wth + gb, smem.stage[0][2] + ls);
        g2lds16(wtl + gb, smem.stage[0][3] + ls);
    }
    __syncthreads();  // drain prime DMA

    int cur = 0;
    for (int k0 = 0; k0 < kVIS; k0 += 64) {
        // prefetch next slab into the idle buffer (flies during this slab's compute)
        if (k0 + 64 < kVIS) {
            const int ko = k0 + 64;
            g2lds16(vh + ga + ko,  smem.stage[cur ^ 1][0] + ls);
            g2lds16(vl + ga + ko,  smem.stage[cur ^ 1][1] + ls);
            g2lds16(wth + gb + ko, smem.stage[cur ^ 1][2] + ls);
            g2lds16(wtl + gb + ko, smem.stage[cur ^ 1][3] + ls);
        }
        const unsigned short* Ah = smem.stage[cur][0];
        const unsigned short* Al = smem.stage[cur][1];
        const unsigned short* Bh = smem.stage[cur][2];
        const unsigned short* Bl = smem.stage[cur][3];
        // 8 frag reads (A:4, B:4) for this wave's 32x32 quadrant, K=32 half
        const bf16x8 a_h0 = *(const bf16x8*)(Ah + ar0 + p);
        const bf16x8 a_h1 = *(const bf16x8*)(Ah + ar1 + p);
        const bf16x8 a_l0 = *(const bf16x8*)(Al + ar0 + p);
        const bf16x8 a_l1 = *(const bf16x8*)(Al + ar1 + p);
        const bf16x8 b_h0 = *(const bf16x8*)(Bh + br0 + p);
        const bf16x8 b_h1 = *(const bf16x8*)(Bh + br1 + p);
        const bf16x8 b_l0 = *(const bf16x8*)(Bl + br0 + p);
        const bf16x8 b_l1 = *(const bf16x8*)(Bl + br1 + p);
        // 12 MFMA: 2 m-tiles x 2 n-tiles x {hh, hl, lh}
        acc[0][0] = __builtin_amdgcn_mfma_f32_16x16x32_bf16(a_h0, b_h0, acc[0][0], 0, 0, 0);
        acc[0][0] = __builtin_amdgcn_mfma_f32_16x16x32_bf16(a_h0, b_l0, acc[0][0], 0, 0, 0);
        acc[0][0] = __builtin_amdgcn_mfma_f32_16x16x32_bf16(a_l0, b_h0, acc[0][0], 0, 0, 0);
        acc[0][1] = __builtin_amdgcn_mfma_f32_16x16x32_bf16(a_h0, b_h1, acc[0][1], 0, 0, 0);
        acc[0][1] = __builtin_amdgcn_mfma_f32_16x16x32_bf16(a_h0, b_l1, acc[0][1], 0, 0, 0);
        acc[0][1] = __builtin_amdgcn_mfma_f32_16x16x32_bf16(a_l0, b_h1, acc[0][1], 0, 0, 0);
        acc[1][0] = __builtin_amdgcn_mfma_f32_16x16x32_bf16(a_h1, b_h0, acc[1][0], 0, 0, 0);
        acc[1][0] = __builtin_amdgcn_mfma_f32_16x16x32_bf16(a_h1, b_l0, acc[1][0], 0, 0, 0);
        acc[1][0] = __builtin_amdgcn_mfma_f32_16x16x32_bf16(a_l1, b_h0, acc[1][0], 0, 0, 0);
        acc[1][1] = __builtin_amdgcn_mfma_f32_16x16x32_bf16(a_h1, b_h1, acc[1][1], 0, 0, 0);
        acc[1][1] = __builtin_amdgcn_mfma_f32_16x16x32_bf16(a_h1, b_l1, acc[1][1], 0, 0, 0);
        acc[1][1] = __builtin_amdgcn_mfma_f32_16x16x32_bf16(a_l1, b_h1, acc[1][1], 0, 0, 0);
        // single barrier per slab: waves done reading cur; prefetch DMA drained
        __syncthreads();
        cur ^= 1;
    }

    // ---- epilogue phase 1: k-half partials -> psH[kh] (log2 domain; c added once, kh=0)
#pragma unroll
    for (int j = 0; j < 2; ++j) {
        const int col = nh * 32 + j * 16 + fm;         // local hid col 0..63
        const float cadd = kh ? 0.f : cvec[n0 + col];
#pragma unroll
        for (int i = 0; i < 2; ++i) {
            const int rbase = mh * 32 + i * 16 + fq * 4;  // local row
#pragma unroll
            for (int rr = 0; rr < 4; ++rr)
                smem.psH[kh][rbase + rr][col] = (acc[i][j][rr] + cadd) * kLog2e;
        }
    }
    __syncthreads();

    // ---- merge k-half planes once (psH[0] += psH[1])
#pragma unroll
    for (int s = 0; s < 2; ++s) {
        const int id = tid + (s << 9);                 // 0..1023
        const int row = id >> 4, q = id & 15;
        float4* d = (float4*)&smem.psH[0][row][q << 2];
        const float4* a = (const float4*)&smem.psH[1][row][q << 2];
        const float4 va = *a, vd = *d;
        *d = make_float4(vd.x + va.x, vd.y + va.y, vd.z + va.z, vd.w + va.w);
    }
    __syncthreads();

    // ---- epilogue phase 2: packed-f32 softplus; wave owns rows [wave*8,+8), lane=class
    const int q0 = (n0 >> 2);
    f32x2 relu2[8], prod2[8];
#pragma unroll
    for (int rr = 0; rr < 8; ++rr) { relu2[rr] = (f32x2)(0.f); prod2[rr] = (f32x2)(1.f); }

    const f32x2 zero2 = (f32x2)(0.f);
    for (int jc = 0; jc < 64; jc += 8) {
        const float4 ua = ((const float4*)Utp)[(q0 + (jc >> 2) + 0) * kCLS + lane];
        const float4 ub = ((const float4*)Utp)[(q0 + (jc >> 2) + 1) * kCLS + lane];
        const f32x2 u01 = {ua.x, ua.y}, u23 = {ua.z, ua.w};
        const f32x2 u45 = {ub.x, ub.y}, u67 = {ub.z, ub.w};
#pragma unroll
        for (int rr = 0; rr < 8; ++rr) {
            const int row = wave * 8 + rr;
            const float4 p0 = *(const float4*)&smem.psH[0][row][jc];      // broadcast
            const float4 p1 = *(const float4*)&smem.psH[0][row][jc + 4];  // broadcast
            f32x2 tp[4];
            tp[0] = (f32x2){p0.x, p0.y} + u01;
            tp[1] = (f32x2){p0.z, p0.w} + u23;
            tp[2] = (f32x2){p1.x, p1.y} + u45;
            tp[3] = (f32x2){p1.z, p1.w} + u67;
#pragma unroll
            for (int g = 0; g < 4; ++g) {
                const f32x2 t = tp[g];
                f32x2 e;
                e.x = __builtin_amdgcn_exp2f(-__builtin_fabsf(t.x));
                e.y = __builtin_amdgcn_exp2f(-__builtin_fabsf(t.y));
                prod2[rr] = __builtin_elementwise_fma(prod2[rr], e, prod2[rr]);  // *= (1+e)
                relu2[rr] += __builtin_elementwise_max(t, zero2);
            }
        }
    }
#pragma unroll
    for (int rr = 0; rr < 8; ++rr) {
        const float contrib = relu2[rr].x + relu2[rr].y +
                              __builtin_amdgcn_logf(prod2[rr].x * prod2[rr].y);  // log2 domain
        Fpart[((size_t)ncol * kB + m0 + wave * 8 + rr) * kCLS + lane] = contrib;
    }

    cg::this_grid().sync();   // all Fpart partials visible

    // ---------------- phase 3: final reduce + softmax + argmax (4 rows/block) ---------
    if (wave < 4) {
        const int row = bid * 4 + wave;
        double s = 0.0;
#pragma unroll
        for (int k = 0; k < kHID / 64; ++k)
            s += (double)Fpart[((size_t)k * kB + row) * kCLS + lane];
        const float G = (float)s + dvec[lane] * kLog2e;  // log2-domain logit

        float m = G;
        int mi = lane;
#pragma unroll
        for (int off = 32; off; off >>= 1) {
            const float om = __shfl_xor(m, off);
            const int   oi = __shfl_xor(mi, off);
            if (om > m || (om == m && oi < mi)) { m = om; mi = oi; }  // first-index tie-break
        }
        const float e2 = __builtin_amdgcn_exp2f(G - m);
        float ssum = e2;
#pragma unroll
        for (int off = 32; off; off >>= 1) ssum += __shfl_xor(ssum, off);
        out[(size_t)row * kCLS + lane] = e2 / ssum;
        out[(size_t)kB * kCLS + (size_t)row * kCLS + lane] = (lane == mi) ? 1.0f : 0.0f;
    }
}

// ================= Proven 3-kernel path (R4, 130 us) — fallback if coop launch fails ====
__global__ __launch_bounds__(256) void prep_all(const float* __restrict__ v,
                                                const float* __restrict__ W,
                                                const float* __restrict__ U,
                                                unsigned short* __restrict__ vh,
                                                unsigned short* __restrict__ vl,
                                                unsigned short* __restrict__ wth,
                                                unsigned short* __restrict__ wtl,
                                                float* __restrict__ Utp) {
    __shared__ float T[64][65];
    const int bx = blockIdx.x;
    if (bx < 4096) {
        const int i = (bx * 256 + threadIdx.x) * 4;
        const float4 xv = *(const float4*)(v + i);
        ushort4 h, l;
        h.x = f2bf(xv.x); l.x = f2bf(xv.x - bf2f(h.x));
        h.y = f2bf(xv.y); l.y = f2bf(xv.y - bf2f(h.y));
        h.z = f2bf(xv.z); l.z = f2bf(xv.z - bf2f(h.z));
        h.w = f2bf(xv.w); l.w = f2bf(xv.w - bf2f(h.w));
        *(ushort4*)(vh + i) = h;
        *(ushort4*)(vl + i) = l;
    } else if (bx < 4608) {
        const int b = bx - 4096;                 // 0..511
        const int n0 = (b & 15) * 64;            // 16 n-tiles
        const int k0 = (b >> 4) * 64;            // 32 k-tiles
        const int c = threadIdx.x & 63, r0 = threadIdx.x >> 6;  // lane, wave
#pragma unroll
        for (int ps = 0; ps < 16; ++ps) {
            const int r = r0 + ps * 4;           // tile row (k)
            T[r][c] = W[(size_t)(k0 + r) * kHID + n0 + c];   // 256 B/wave, coalesced
        }
        __syncthreads();
#pragma unroll
        for (int ps = 0; ps < 16; ++ps) {
            const int nn = r0 + ps * 4;          // tile row (n) of output
            const float x = T[c][nn];            // 2-way bank alias
            const unsigned short h = f2bf(x);
            const unsigned short l = f2bf(x - bf2f(h));
            const size_t o = (size_t)(n0 + nn) * kVIS + k0 + c;
            wth[o] = h;                          // 128 B/wave, coalesced
            wtl[o] = l;
        }
    } else {
        const int id = (bx - 4608) * 256 + threadIdx.x;  // 0..65535
        const int j = id >> 6, y = id & 63;
        Utp[(((j >> 2) * kCLS + y) << 2) + (j & 3)] = U[(size_t)y * kHID + j] * kLog2e;
    }
}

__global__ __launch_bounds__(512, 4) void gemm_fused(const unsigned short* __restrict__ vh,
                                                     const unsigned short* __restrict__ vl,
                                                     const unsigned short* __restrict__ wth,
                                                     const unsigned short* __restrict__ wtl,
                                                     const float* __restrict__ cvec,
                                                     const float* __restrict__ Utp,
                                                     float* __restrict__ Fpart) {
    __shared__ __align__(16) union SMem {
        unsigned short stage[2][4][64 * 64];
        float psH[2][64][68];
    } smem;

    const int tid = threadIdx.x;
    const int lane = tid & 63, wave = tid >> 6;
    const int mh = wave >> 2;
    const int nh = (wave >> 1) & 1;
    const int kh = wave & 1;

    const int bid = blockIdx.x;
    const int idx = bid >> 3;
    const int mstripe = ((bid & 7) << 2) + (idx >> 4);
    const int ncol = idx & 15;
    const int m0 = mstripe * 64, n0 = ncol * 64;

    const int r = tid >> 3;
    const int oc = (((tid & 7) ^ ((tid >> 3) & 7)) << 3);
    const size_t ga = (size_t)(m0 + r) * kVIS + oc;
    const size_t gb = (size_t)(n0 + r) * kVIS + oc;
    const int ls = (r << 6) + ((tid & 7) << 3);

    const int fm = lane & 15, fq = lane >> 4;
    const int rx = fm & 7;
    const int ar0 = (mh * 32 + fm) << 6, ar1 = (mh * 32 + 16 + fm) << 6;
    const int br0 = (nh * 32 + fm) << 6, br1 = (nh * 32 + 16 + fm) << 6;
    const int p = (((kh << 2) + fq) ^ rx) << 3;

    f32x4 acc[2][2] = {};

    {
        g2lds16(vh + ga,  smem.stage[0][0] + ls);
        g2lds16(vl + ga,  smem.stage[0][1] + ls);
        g2lds16(wth + gb, smem.stage[0][2] + ls);
        g2lds16(wtl + gb, smem.stage[0][3] + ls);
    }
    __syncthreads();

    int cur = 0;
    for (int k0 = 0; k0 < kVIS; k0 += 64) {
        if (k0 + 64 < kVIS) {
            const int ko = k0 + 64;
            g2lds16(vh + ga + ko,  smem.stage[cur ^ 1][0] + ls);
            g2lds16(vl + ga + ko,  smem.stage[cur ^ 1][1] + ls);
            g2lds16(wth + gb + ko, smem.stage[cur ^ 1][2] + ls);
            g2lds16(wtl + gb + ko, smem.stage[cur ^ 1][3] + ls);
        }
        const unsigned short* Ah = smem.stage[cur][0];
        const unsigned short* Al = smem.stage[cur][1];
        const unsigned short* Bh = smem.stage[cur][2];
        const unsigned short* Bl = smem.stage[cur][3];
        const bf16x8 a_h0 = *(const bf16x8*)(Ah + ar0 + p);
        const bf16x8 a_h1 = *(const bf16x8*)(Ah + ar1 + p);
        const bf16x8 a_l0 = *(const bf16x8*)(Al + ar0 + p);
        const bf16x8 a_l1 = *(const bf16x8*)(Al + ar1 + p);
        const bf16x8 b_h0 = *(const bf16x8*)(Bh + br0 + p);
        const bf16x8 b_h1 = *(const bf16x8*)(Bh + br1 + p);
        const bf16x8 b_l0 = *(const bf16x8*)(Bl + br0 + p);
        const bf16x8 b_l1 = *(const bf16x8*)(Bl + br1 + p);
        acc[0][0] = __builtin_amdgcn_mfma_f32_16x16x32_bf16(a_h0, b_h0, acc[0][0], 0, 0, 0);
        acc[0][0] = __builtin_amdgcn_mfma_f32_16x16x32_bf16(a_h0, b_l0, acc[0][0], 0, 0, 0);
        acc[0][0] = __builtin_amdgcn_mfma_f32_16x16x32_bf16(a_l0, b_h0, acc[0][0], 0, 0, 0);
        acc[0][1] = __builtin_amdgcn_mfma_f32_16x16x32_bf16(a_h0, b_h1, acc[0][1], 0, 0, 0);
        acc[0][1] = __builtin_amdgcn_mfma_f32_16x16x32_bf16(a_h0, b_l1, acc[0][1], 0, 0, 0);
        acc[0][1] = __builtin_amdgcn_mfma_f32_16x16x32_bf16(a_l0, b_h1, acc[0][1], 0, 0, 0);
        acc[1][0] = __builtin_amdgcn_mfma_f32_16x16x32_bf16(a_h1, b_h0, acc[1][0], 0, 0, 0);
        acc[1][0] = __builtin_amdgcn_mfma_f32_16x16x32_bf16(a_h1, b_l0, acc[1][0], 0, 0, 0);
        acc[1][0] = __builtin_amdgcn_mfma_f32_16x16x32_bf16(a_l1, b_h0, acc[1][0], 0, 0, 0);
        acc[1][1] = __builtin_amdgcn_mfma_f32_16x16x32_bf16(a_h1, b_h1, acc[1][1], 0, 0, 0);
        acc[1][1] = __builtin_amdgcn_mfma_f32_16x16x32_bf16(a_h1, b_l1, acc[1][1], 0, 0, 0);
        acc[1][1] = __builtin_amdgcn_mfma_f32_16x16x32_bf16(a_l1, b_h1, acc[1][1], 0, 0, 0);
        __syncthreads();
        cur ^= 1;
    }

#pragma unroll
    for (int j = 0; j < 2; ++j) {
        const int col = nh * 32 + j * 16 + fm;
        const float cadd = kh ? 0.f : cvec[n0 + col];
#pragma unroll
        for (int i = 0; i < 2; ++i) {
            const int rbase = mh * 32 + i * 16 + fq * 4;
#pragma unroll
            for (int rr = 0; rr < 4; ++rr)
                smem.psH[kh][rbase + rr][col] = (acc[i][j][rr] + cadd) * kLog2e;
        }
    }
    __syncthreads();

#pragma unroll
    for (int s = 0; s < 2; ++s) {
        const int id = tid + (s << 9);
        const int row = id >> 4, q = id & 15;
        float4* d = (float4*)&smem.psH[0][row][q << 2];
        const float4* a = (const float4*)&smem.psH[1][row][q << 2];
        const float4 va = *a, vd = *d;
        *d = make_float4(vd.x + va.x, vd.y + va.y, vd.z + va.z, vd.w + va.w);
    }
    __syncthreads();

    const int q0 = (n0 >> 2);
    f32x2 relu2[8], prod2[8];
#pragma unroll
    for (int rr = 0; rr < 8; ++rr) { relu2[rr] = (f32x2)(0.f); prod2[rr] = (f32x2)(1.f); }

    const f32x2 zero2 = (f32x2)(0.f);
    for (int jc = 0; jc < 64; jc += 8) {
        const float4 ua = ((const float4*)Utp)[(q0 + (jc >> 2) + 0) * kCLS + lane];
        const float4 ub = ((const float4*)Utp)[(q0 + (jc >> 2) + 1) * kCLS + lane];
        const f32x2 u01 = {ua.x, ua.y}, u23 = {ua.z, ua.w};
        const f32x2 u45 = {ub.x, ub.y}, u67 = {ub.z, ub.w};
#pragma unroll
        for (int rr = 0; rr < 8; ++rr) {
            const int row = wave * 8 + rr;
            const float4 p0 = *(const float4*)&smem.psH[0][row][jc];
            const float4 p1 = *(const float4*)&smem.psH[0][row][jc + 4];
            f32x2 tp[4];
            tp[0] = (f32x2){p0.x, p0.y} + u01;
            tp[1] = (f32x2){p0.z, p0.w} + u23;
            tp[2] = (f32x2){p1.x, p1.y} + u45;
            tp[3] = (f32x2){p1.z, p1.w} + u67;
#pragma unroll
            for (int g = 0; g < 4; ++g) {
                const f32x2 t = tp[g];
                f32x2 e;
                e.x = __builtin_amdgcn_exp2f(-__builtin_fabsf(t.x));
                e.y = __builtin_amdgcn_exp2f(-__builtin_fabsf(t.y));
                prod2[rr] = __builtin_elementwise_fma(prod2[rr], e, prod2[rr]);
                relu2[rr] += __builtin_elementwise_max(t, zero2);
            }
        }
    }
#pragma unroll
    for (int rr = 0; rr < 8; ++rr) {
        const float contrib = relu2[rr].x + relu2[rr].y +
                              __builtin_amdgcn_logf(prod2[rr].x * prod2[rr].y);
        Fpart[((size_t)ncol * kB + m0 + wave * 8 + rr) * kCLS + lane] = contrib;
    }
}

__global__ __launch_bounds__(256) void softmax_final(const float* __restrict__ Fpart,
                                                     const float* __restrict__ dvec,
                                                     float* __restrict__ out) {
    const int tid = threadIdx.x;
    const int lane = tid & 63, wave = tid >> 6;
    const int row = blockIdx.x * 4 + wave;
    double s = 0.0;
#pragma unroll
    for (int k = 0; k < kHID / 64; ++k)
        s += (double)Fpart[((size_t)k * kB + row) * kCLS + lane];
    const float G = (float)s + dvec[lane] * kLog2e;

    float m = G;
    int mi = lane;
#pragma unroll
    for (int off = 32; off; off >>= 1) {
        const float om = __shfl_xor(m, off);
        const int   oi = __shfl_xor(mi, off);
        if (om > m || (om == m && oi < mi)) { m = om; mi = oi; }
    }
    const float e2 = __builtin_amdgcn_exp2f(G - m);
    float ssum = e2;
#pragma unroll
    for (int off = 32; off; off >>= 1) ssum += __shfl_xor(ssum, off);
    out[(size_t)row * kCLS + lane] = e2 / ssum;
    out[(size_t)kB * kCLS + (size_t)row * kCLS + lane] = (lane == mi) ? 1.0f : 0.0f;
}

// ================= Fallback (round-1, known-passing) if ws is too small =================
constexpr int BM = 64, BN = 64, BK = 16;

__global__ __launch_bounds__(256) void gemm_vw(const float* __restrict__ V,
                                               const float* __restrict__ Wm,
                                               const float* __restrict__ cvec,
                                               float* __restrict__ pre) {
    __shared__ float As[BK][BM + 4];
    __shared__ float Bs[BK][BN + 4];
    const int tid = threadIdx.x;
    const int tx = tid & 15, ty = tid >> 4;
    const int m0 = blockIdx.y * BM, n0 = blockIdx.x * BN;
    const int arow = tid >> 2, acol = (tid & 3) << 2;
    const int brow = tid >> 4, bcol = (tid & 15) << 2;
    const float* vptr = V + (size_t)(m0 + arow) * kVIS + acol;
    const float* wptr = Wm + (size_t)brow * kHID + n0 + bcol;
    float acc[4][4] = {};
    for (int k0 = 0; k0 < kVIS; k0 += BK) {
        const float4 a4 = *(const float4*)(vptr + k0);
        const float4 b4 = *(const float4*)(wptr + (size_t)k0 * kHID);
        __syncthreads();
        As[acol + 0][arow] = a4.x; As[acol + 1][arow] = a4.y;
        As[acol + 2][arow] = a4.z; As[acol + 3][arow] = a4.w;
        *(float4*)&Bs[brow][bcol] = b4;
        __syncthreads();
#pragma unroll
        for (int k = 0; k < BK; ++k) {
            const float4 av = *(const float4*)&As[k][ty << 2];
            const float4 bv = *(const float4*)&Bs[k][tx << 2];
            const float a[4] = {av.x, av.y, av.z, av.w};
            const float b[4] = {bv.x, bv.y, bv.z, bv.w};
#pragma unroll
            for (int i = 0; i < 4; ++i)
#pragma unroll
                for (int j = 0; j < 4; ++j) acc[i][j] += a[i] * b[j];
        }
    }
#pragma unroll
    for (int i = 0; i < 4; ++i) {
        const int row = m0 + (ty << 2) + i;
        const int col = n0 + (tx << 2);
        const float4 cv = *(const float4*)(cvec + col);
        float4 o;
        o.x = acc[i][0] + cv.x; o.y = acc[i][1] + cv.y;
        o.z = acc[i][2] + cv.z; o.w = acc[i][3] + cv.w;
        *(float4*)(pre + (size_t)row * kHID + col) = o;
    }
}

__device__ __forceinline__ float softplus_f(float x) {
    return fmaxf(x, 0.f) + __logf(1.f + __expf(-fabsf(x)));
}

__global__ __launch_bounds__(256) void classify(const float* __restrict__ pre,
                                                const float* __restrict__ U,
                                                const float* __restrict__ dvec,
                                                float* __restrict__ out) {
    __shared__ float preS[4][kHID];
    __shared__ float Fs[4][kCLS];
    const int tid = threadIdx.x;
    const int lane = tid & 63, wave = tid >> 6;
    const int b0 = blockIdx.x * 4;
    const float4* src = (const float4*)(pre + (size_t)b0 * kHID);
    float4* dst = (float4*)preS;
    for (int i = tid; i < kHID; i += 256) dst[i] = src[i];
    __syncthreads();
    for (int yi = 0; yi < 16; ++yi) {
        const int y = (wave << 4) + yi;
        const float* Uy = U + (size_t)y * kHID;
        float a0 = 0.f, a1 = 0.f, a2 = 0.f, a3 = 0.f;
#pragma unroll
        for (int it = 0; it < kHID / 64; ++it) {
            const int j = lane + (it << 6);
            const float u = Uy[j];
            a0 += softplus_f(preS[0][j] + u);
            a1 += softplus_f(preS[1][j] + u);
            a2 += softplus_f(preS[2][j] + u);
            a3 += softplus_f(preS[3][j] + u);
        }
        double d0 = a0, d1 = a1, d2 = a2, d3 = a3;
#pragma unroll
        for (int off = 32; off; off >>= 1) {
            d0 += __shfl_xor(d0, off); d1 += __shfl_xor(d1, off);
            d2 += __shfl_xor(d2, off); d3 += __shfl_xor(d3, off);
        }
        if (lane == 0) {
            const float dy = dvec[y];
            Fs[0][y] = (float)d0 + dy; Fs[1][y] = (float)d1 + dy;
            Fs[2][y] = (float)d2 + dy; Fs[3][y] = (float)d3 + dy;
        }
    }
    __syncthreads();
    const float F = Fs[wave][lane];
    float m = F; int mi = lane;
#pragma unroll
    for (int off = 32; off; off >>= 1) {
        const float om = __shfl_xor(m, off);
        const int oi = __shfl_xor(mi, off);
        if (om > m || (om == m && oi < mi)) { m = om; mi = oi; }
    }
    const float e = __expf(F - m);
    float s = e;
#pragma unroll
    for (int off = 32; off; off >>= 1) s += __shfl_xor(s, off);
    const int row = b0 + wave;
    out[(size_t)row * kCLS + lane] = e / s;
    out[(size_t)kB * kCLS + (size_t)row * kCLS + lane] = (lane == mi) ? 1.0f : 0.0f;
}

extern "C" void kernel_launch(void* const* d_in, const int* in_sizes, int n_in,
                              void* d_out, int out_size, void* d_ws, size_t ws_size,
                              hipStream_t stream) {
    const float* v = (const float*)d_in[0];
    const float* W = (const float*)d_in[1];
    const float* c = (const float*)d_in[2];
    const float* d = (const float*)d_in[3];
    const float* U = (const float*)d_in[4];
    float* out = (float*)d_out;
    char* ws = (char*)d_ws;

    // ws layout: vh 8MB | vl 8MB | Wt_h 4MB | Wt_l 4MB | Utp 256KB | Fpart 8MB
    const size_t need = 33816576;
    if (ws_size >= need) {
        unsigned short* vh  = (unsigned short*)(ws);
        unsigned short* vl  = (unsigned short*)(ws + 8388608);
        unsigned short* wth = (unsigned short*)(ws + 16777216);
        unsigned short* wtl = (unsigned short*)(ws + 20971520);
        float* Utp   = (float*)(ws + 25165824);
        float* Fpart = (float*)(ws + 25427968);

        void* kargs[] = {(void*)&v, (void*)&W, (void*)&U, (void*)&c, (void*)&d,
                         (void*)&vh, (void*)&vl, (void*)&wth, (void*)&wtl,
                         (void*)&Utp, (void*)&Fpart, (void*)&out};
        hipError_t err = hipLaunchCooperativeKernel((const void*)fused_all,
                                                    dim3(512), dim3(512),
                                                    kargs, 0, stream);
        if (err != hipSuccess) {
            // proven 3-kernel path (R4: 130 us)
            prep_all<<<4864, 256, 0, stream>>>(v, W, U, vh, vl, wth, wtl, Utp);
            gemm_fused<<<512, 512, 0, stream>>>(vh, vl, wth, wtl, c, Utp, Fpart);
            softmax_final<<<kB / 4, 256, 0, stream>>>(Fpart, d, out);
        }
    } else {
        float* pre = (float*)ws;
        gemm_vw<<<dim3(kHID / BN, kB / BM), 256, 0, stream>>>(v, W, c, pre);
        classify<<<kB / 4, 256, 0, stream>>>(pre, U, d, out);
    }
}

// Round 6
// 135.980 us; speedup vs baseline: 1.8545x; 1.8545x over previous
//
#include <hip/hip_runtime.h>

// Problem sizes (fixed by the reference)
constexpr int kB    = 2048;  // batch
constexpr int kVIS  = 2048;  // visible units (GEMM K)
constexpr int kHID  = 1024;  // hidden units (GEMM N)
constexpr int kCLS  = 64;    // classes
constexpr float kLog2e = 1.4426950408889634f;

typedef __attribute__((ext_vector_type(8))) short bf16x8;
typedef __attribute__((ext_vector_type(4))) float f32x4;
typedef __attribute__((ext_vector_type(2))) float f32x2;

typedef __attribute__((address_space(3))) unsigned       as3_u32;
typedef __attribute__((address_space(1))) const unsigned as1_u32;

__device__ __forceinline__ void g2lds16(const void* g, void* l) {
    // async global->LDS DMA, 16 B per lane; LDS dest is wave-base + lane*16
    __builtin_amdgcn_global_load_lds((as1_u32*)g, (as3_u32*)l, 16, 0, 0);
}

__device__ __forceinline__ unsigned short f2bf(float x) {
    unsigned u = __float_as_uint(x);
    u += 0x7fffu + ((u >> 16) & 1u);
    return (unsigned short)(u >> 16);
}
__device__ __forceinline__ float bf2f(unsigned short h) {
    return __uint_as_float(((unsigned)h) << 16);
}

// ---------------- Prep (merged): split v, split+transpose W, pack+scale U ----------------
// R4 version, unchanged (proven). Global layouts of vh/vl/wth/wtl unchanged — the new
// gemm staging applies its swizzle on the DMA source addresses, not on the arrays.
__global__ __launch_bounds__(256) void prep_all(const float* __restrict__ v,
                                                const float* __restrict__ W,
                                                const float* __restrict__ U,
                                                unsigned short* __restrict__ vh,
                                                unsigned short* __restrict__ vl,
                                                unsigned short* __restrict__ wth,
                                                unsigned short* __restrict__ wtl,
                                                float* __restrict__ Utp) {
    __shared__ float T[64][65];
    const int bx = blockIdx.x;
    if (bx < 4096) {
        const int i = (bx * 256 + threadIdx.x) * 4;
        const float4 xv = *(const float4*)(v + i);
        ushort4 h, l;
        h.x = f2bf(xv.x); l.x = f2bf(xv.x - bf2f(h.x));
        h.y = f2bf(xv.y); l.y = f2bf(xv.y - bf2f(h.y));
        h.z = f2bf(xv.z); l.z = f2bf(xv.z - bf2f(h.z));
        h.w = f2bf(xv.w); l.w = f2bf(xv.w - bf2f(h.w));
        *(ushort4*)(vh + i) = h;
        *(ushort4*)(vl + i) = l;
    } else if (bx < 4608) {
        const int b = bx - 4096;                 // 0..511
        const int n0 = (b & 15) * 64;            // 16 n-tiles
        const int k0 = (b >> 4) * 64;            // 32 k-tiles
        const int c = threadIdx.x & 63, r0 = threadIdx.x >> 6;  // lane, wave
#pragma unroll
        for (int ps = 0; ps < 16; ++ps) {
            const int r = r0 + ps * 4;           // tile row (k)
            T[r][c] = W[(size_t)(k0 + r) * kHID + n0 + c];   // 256 B/wave, coalesced
        }
        __syncthreads();
#pragma unroll
        for (int ps = 0; ps < 16; ++ps) {
            const int nn = r0 + ps * 4;          // tile row (n) of output
            const float x = T[c][nn];            // = W[k0+c][n0+nn], 2-way bank alias
            const unsigned short h = f2bf(x);
            const unsigned short l = f2bf(x - bf2f(h));
            const size_t o = (size_t)(n0 + nn) * kVIS + k0 + c;
            wth[o] = h;                          // 128 B/wave, coalesced
            wtl[o] = l;
        }
    } else {
        const int id = (bx - 4608) * 256 + threadIdx.x;  // 0..65535
        const int j = id >> 6, y = id & 63;
        // packed: Utp[((j>>2)*64 + y)*4 + (j&3)]  ->  one dwordx4 per (j-quad, class)
        Utp[(((j >> 2) * kCLS + y) << 2) + (j & 3)] = U[(size_t)y * kHID + j] * kLog2e;
    }
}

// ---------------- Fused kernel: split-bf16 MFMA GEMM + softplus partial-F epilogue ------
// R16: 4-buffer K=32 counted-vmcnt pipeline (T3/T4). The proven R0 structure was
// latency-bound: 3825 cyc/slab measured vs ~930 MFMA + ~770 LDS of work — the
// __syncthreads() (= vmcnt(0) drain) exposed HBM latency every slab, since the 2-buffer
// dbuf loads slab k+1 during slab k. Now: slabs of K=32 (16 KB), 4 LDS buffers (same
// 64 KB total -> same 2 blocks/CU, 16 waves/CU), loads issued 2 slabs ahead, and the
// per-slab sync is `s_waitcnt vmcnt(4)` + raw s_barrier — never vmcnt(0) in-loop.
// Wave split: mh(2) x nh(2) x slab-parity(2): parity-p waves compute slabs p,p+2,...
// each doing the full 32x32 quadrant (8 frag reads / 12 MFMA — R0's proven ratio).
// LDS per slab-buffer: A[64 rows][128 B] ++ B[64][128 B]; row = 8 16B-positions, position
// q holds logical u = q ^ (row&7) (u<4: h-octet u, u>=4: l-octet u-4) — 8-slot XOR
// swizzle keeps frag ds_read_b128 2-way (free) and the DMA dest linear (source-side
// swizzle per m173). Epilogue identical to R0 (psH plane = parity instead of k-half).
__global__ __launch_bounds__(512, 4) void gemm_fused(const unsigned short* __restrict__ vh,
                                                     const unsigned short* __restrict__ vl,
                                                     const unsigned short* __restrict__ wth,
                                                     const unsigned short* __restrict__ wtl,
                                                     const float* __restrict__ cvec,
                                                     const float* __restrict__ Utp,
                                                     float* __restrict__ Fpart) {
    __shared__ __align__(16) union SMem {
        unsigned short stage[4][8192];        // 4 bufs x 16 KB (A 8KB ++ B 8KB) = 65536 B
        float psH[2][64][68];                 // 34816 B, overlays stage
    } smem;

    const int tid = threadIdx.x;
    const int lane = tid & 63, wave = tid >> 6;   // wave 0..7
    const int mh = wave >> 2;                     // m-half: rows mh*32..+32
    const int nh = (wave >> 1) & 1;               // n-half: cols nh*32..+32
    const int pw = wave & 1;                      // slab parity this wave computes

    // XCD-aware decomposition of the 1D grid (512 blocks, 32 m-stripes x 16 n-tiles)
    const int bid = blockIdx.x;
    const int idx = bid >> 3;                           // 0..63
    const int mstripe = ((bid & 7) << 2) + (idx >> 4);  // 0..31
    const int ncol = idx & 15;                          // 0..15
    const int m0 = mstripe * 64, n0 = ncol * 64;

    unsigned short* const st = &smem.stage[0][0];

    // --- staging map: thread t covers 16B position q=(t&7) of row r=(t>>3) in both the
    // A-plane (elems [0,4096)) and B-plane ([4096,8192)) of each slab buffer.
    // Logical content u = q ^ (r&7): u<4 -> h-plane octet u ; u>=4 -> l-plane octet u-4.
    {
    }
    const int sr = tid >> 3;                      // row 0..63
    const int sq = tid & 7;                       // 16B position in row
    const int su = sq ^ (sr & 7);                 // logical slot
    const int soct = su & 3;                      // k-octet within slab
    const unsigned short* srcA =
        ((su >> 2) ? vl : vh) + (size_t)(m0 + sr) * kVIS + (soct << 3);
    const unsigned short* srcB =
        ((su >> 2) ? wtl : wth) + (size_t)(n0 + sr) * kVIS + (soct << 3);
    const int lsA = tid << 3;                     // elems; lane-linear 16B slots
    const int lsB = 4096 + (tid << 3);

    // --- fragment addressing: row R at elems R*64; h-octet fq at position fq^(R&7),
    // l-octet at that ^4 (position*8 elems -> ^32). R&7 == fm&7 (bases are mult of 16).
    const int fm = lane & 15, fq = lane >> 4;
    const int ph = ((fq ^ (fm & 7)) << 3);
    const int pl = ph ^ 32;
    const int ar0 = (mh * 32 + fm) << 6, ar1 = ar0 + 1024;
    const int br0 = 4096 + ((nh * 32 + fm) << 6), br1 = br0 + 1024;

    f32x4 acc[2][2] = {};   // [m-tile][n-tile], 16 VGPRs

    // prologue: issue slabs 0 and 1 (2 loads each -> 4 outstanding per thread)
    g2lds16(srcA, st + lsA);
    g2lds16(srcB, st + lsB);
    g2lds16(srcA + 32, st + 8192 + lsA);
    g2lds16(srcB + 32, st + 8192 + lsB);

    // main loop over 64 K=32 slabs; slab t lives in buffer t&3.
    // tick t: issue slab t+2 | wait vmcnt(4) (own slab-t loads done) | barrier
    //         (everyone's slab-t landed) | parity-(t&1) waves compute slab t.
    // Buffer safety: buf (t+2)&3 was last read at tick t-2; all waves passed
    // barrier(t-1) after those reads retired (lgkm waits precede it), and the issue
    // at tick t follows barrier(t-1) in program order.
    for (int t = 0; t < 62; ++t) {
        const int koff = (t + 2) << 5;
        unsigned short* const dst = st + (((t + 2) & 3) << 13);
        g2lds16(srcA + koff, dst + lsA);
        g2lds16(srcB + koff, dst + lsB);
        asm volatile("s_waitcnt vmcnt(4)" ::: "memory");
        __builtin_amdgcn_s_barrier();
        if (pw == (t & 1)) {
            const unsigned short* buf = st + ((t & 3) << 13);
            const bf16x8 a_h0 = *(const bf16x8*)(buf + ar0 + ph);
            const bf16x8 a_l0 = *(const bf16x8*)(buf + ar0 + pl);
            const bf16x8 a_h1 = *(const bf16x8*)(buf + ar1 + ph);
            const bf16x8 a_l1 = *(const bf16x8*)(buf + ar1 + pl);
            const bf16x8 b_h0 = *(const bf16x8*)(buf + br0 + ph);
            const bf16x8 b_l0 = *(const bf16x8*)(buf + br0 + pl);
            const bf16x8 b_h1 = *(const bf16x8*)(buf + br1 + ph);
            const bf16x8 b_l1 = *(const bf16x8*)(buf + br1 + pl);
            acc[0][0] = __builtin_amdgcn_mfma_f32_16x16x32_bf16(a_h0, b_h0, acc[0][0], 0, 0, 0);
            acc[0][0] = __builtin_amdgcn_mfma_f32_16x16x32_bf16(a_h0, b_l0, acc[0][0], 0, 0, 0);
            acc[0][0] = __builtin_amdgcn_mfma_f32_16x16x32_bf16(a_l0, b_h0, acc[0][0], 0, 0, 0);
            acc[0][1] = __builtin_amdgcn_mfma_f32_16x16x32_bf16(a_h0, b_h1, acc[0][1], 0, 0, 0);
            acc[0][1] = __builtin_amdgcn_mfma_f32_16x16x32_bf16(a_h0, b_l1, acc[0][1], 0, 0, 0);
            acc[0][1] = __builtin_amdgcn_mfma_f32_16x16x32_bf16(a_l0, b_h1, acc[0][1], 0, 0, 0);
            acc[1][0] = __builtin_amdgcn_mfma_f32_16x16x32_bf16(a_h1, b_h0, acc[1][0], 0, 0, 0);
            acc[1][0] = __builtin_amdgcn_mfma_f32_16x16x32_bf16(a_h1, b_l0, acc[1][0], 0, 0, 0);
            acc[1][0] = __builtin_amdgcn_mfma_f32_16x16x32_bf16(a_l1, b_h0, acc[1][0], 0, 0, 0);
            acc[1][1] = __builtin_amdgcn_mfma_f32_16x16x32_bf16(a_h1, b_h1, acc[1][1], 0, 0, 0);
            acc[1][1] = __builtin_amdgcn_mfma_f32_16x16x32_bf16(a_h1, b_l1, acc[1][1], 0, 0, 0);
            acc[1][1] = __builtin_amdgcn_mfma_f32_16x16x32_bf16(a_l1, b_h1, acc[1][1], 0, 0, 0);
        }
    }
    // tail: slabs 62 (parity 0, buf 2) and 63 (parity 1, buf 3) — no new issues,
    // different buffers, no writes -> both parities compute concurrently.
    asm volatile("s_waitcnt vmcnt(0)" ::: "memory");
    __builtin_amdgcn_s_barrier();
    {
        const int t = 62 + pw;
        const unsigned short* buf = st + ((t & 3) << 13);
        const bf16x8 a_h0 = *(const bf16x8*)(buf + ar0 + ph);
        const bf16x8 a_l0 = *(const bf16x8*)(buf + ar0 + pl);
        const bf16x8 a_h1 = *(const bf16x8*)(buf + ar1 + ph);
        const bf16x8 a_l1 = *(const bf16x8*)(buf + ar1 + pl);
        const bf16x8 b_h0 = *(const bf16x8*)(buf + br0 + ph);
        const bf16x8 b_l0 = *(const bf16x8*)(buf + br0 + pl);
        const bf16x8 b_h1 = *(const bf16x8*)(buf + br1 + ph);
        const bf16x8 b_l1 = *(const bf16x8*)(buf + br1 + pl);
        acc[0][0] = __builtin_amdgcn_mfma_f32_16x16x32_bf16(a_h0, b_h0, acc[0][0], 0, 0, 0);
        acc[0][0] = __builtin_amdgcn_mfma_f32_16x16x32_bf16(a_h0, b_l0, acc[0][0], 0, 0, 0);
        acc[0][0] = __builtin_amdgcn_mfma_f32_16x16x32_bf16(a_l0, b_h0, acc[0][0], 0, 0, 0);
        acc[0][1] = __builtin_amdgcn_mfma_f32_16x16x32_bf16(a_h0, b_h1, acc[0][1], 0, 0, 0);
        acc[0][1] = __builtin_amdgcn_mfma_f32_16x16x32_bf16(a_h0, b_l1, acc[0][1], 0, 0, 0);
        acc[0][1] = __builtin_amdgcn_mfma_f32_16x16x32_bf16(a_l0, b_h1, acc[0][1], 0, 0, 0);
        acc[1][0] = __builtin_amdgcn_mfma_f32_16x16x32_bf16(a_h1, b_h0, acc[1][0], 0, 0, 0);
        acc[1][0] = __builtin_amdgcn_mfma_f32_16x16x32_bf16(a_h1, b_l0, acc[1][0], 0, 0, 0);
        acc[1][0] = __builtin_amdgcn_mfma_f32_16x16x32_bf16(a_l1, b_h0, acc[1][0], 0, 0, 0);
        acc[1][1] = __builtin_amdgcn_mfma_f32_16x16x32_bf16(a_h1, b_h1, acc[1][1], 0, 0, 0);
        acc[1][1] = __builtin_amdgcn_mfma_f32_16x16x32_bf16(a_h1, b_l1, acc[1][1], 0, 0, 0);
        acc[1][1] = __builtin_amdgcn_mfma_f32_16x16x32_bf16(a_l1, b_h1, acc[1][1], 0, 0, 0);
    }
    __syncthreads();   // all stage reads retired before psH overlays it

    // ---- epilogue phase 1: parity partials -> psH[pw] (log2 domain; c added once, pw=0)
    // for fixed pw, the 4 (mh,nh) waves tile the full 64x64 -> no overlap
#pragma unroll
    for (int j = 0; j < 2; ++j) {
        const int col = nh * 32 + j * 16 + fm;         // local hid col 0..63
        const float cadd = pw ? 0.f : cvec[n0 + col];
#pragma unroll
        for (int i = 0; i < 2; ++i) {
            const int rbase = mh * 32 + i * 16 + fq * 4;  // local row
#pragma unroll
            for (int rr = 0; rr < 4; ++rr)
                smem.psH[pw][rbase + rr][col] = (acc[i][j][rr] + cadd) * kLog2e;
        }
    }
    __syncthreads();

    // ---- merge parity planes once (psH[0] += psH[1]) -> epilogue reads halve.
#pragma unroll
    for (int s = 0; s < 2; ++s) {
        const int id = tid + (s << 9);                 // 0..1023
        const int row = id >> 4, q = id & 15;
        float4* d = (float4*)&smem.psH[0][row][q << 2];
        const float4* a = (const float4*)&smem.psH[1][row][q << 2];
        const float4 va = *a, vd = *d;
        *d = make_float4(vd.x + va.x, vd.y + va.y, vd.z + va.z, vd.w + va.w);
    }
    __syncthreads();

    // ---- epilogue phase 2: packed-f32 softplus; wave owns rows [wave*8,+8), lane=class
    const int q0 = (n0 >> 2);
    f32x2 relu2[8], prod2[8];
#pragma unroll
    for (int rr = 0; rr < 8; ++rr) { relu2[rr] = (f32x2)(0.f); prod2[rr] = (f32x2)(1.f); }

    const f32x2 zero2 = (f32x2)(0.f);
    for (int jc = 0; jc < 64; jc += 8) {
        const float4 ua = ((const float4*)Utp)[(q0 + (jc >> 2) + 0) * kCLS + lane];
        const float4 ub = ((const float4*)Utp)[(q0 + (jc >> 2) + 1) * kCLS + lane];
        const f32x2 u01 = {ua.x, ua.y}, u23 = {ua.z, ua.w};
        const f32x2 u45 = {ub.x, ub.y}, u67 = {ub.z, ub.w};
#pragma unroll
        for (int rr = 0; rr < 8; ++rr) {
            const int row = wave * 8 + rr;
            const float4 p0 = *(const float4*)&smem.psH[0][row][jc];      // broadcast
            const float4 p1 = *(const float4*)&smem.psH[0][row][jc + 4];  // broadcast
            f32x2 tp[4];
            tp[0] = (f32x2){p0.x, p0.y} + u01;
            tp[1] = (f32x2){p0.z, p0.w} + u23;
            tp[2] = (f32x2){p1.x, p1.y} + u45;
            tp[3] = (f32x2){p1.z, p1.w} + u67;
#pragma unroll
            for (int g = 0; g < 4; ++g) {
                const f32x2 t = tp[g];
                f32x2 e;
                e.x = __builtin_amdgcn_exp2f(-__builtin_fabsf(t.x));
                e.y = __builtin_amdgcn_exp2f(-__builtin_fabsf(t.y));
                prod2[rr] = __builtin_elementwise_fma(prod2[rr], e, prod2[rr]);  // *= (1+e)
                relu2[rr] += __builtin_elementwise_max(t, zero2);
            }
        }
    }
#pragma unroll
    for (int rr = 0; rr < 8; ++rr) {
        const float contrib = relu2[rr].x + relu2[rr].y +
                              __builtin_amdgcn_logf(prod2[rr].x * prod2[rr].y);  // log2 domain
        Fpart[((size_t)ncol * kB + m0 + wave * 8 + rr) * kCLS + lane] = contrib;
    }
}

// ---------------- Final: sum 16 partials (double), softmax, argmax, one-hot ------------
__global__ __launch_bounds__(256) void softmax_final(const float* __restrict__ Fpart,
                                                     const float* __restrict__ dvec,
                                                     float* __restrict__ out) {
    const int tid = threadIdx.x;
    const int lane = tid & 63, wave = tid >> 6;
    const int row = blockIdx.x * 4 + wave;
    double s = 0.0;
#pragma unroll
    for (int k = 0; k < kHID / 64; ++k)
        s += (double)Fpart[((size_t)k * kB + row) * kCLS + lane];
    const float G = (float)s + dvec[lane] * kLog2e;  // log2-domain logit

    float m = G;
    int mi = lane;
#pragma unroll
    for (int off = 32; off; off >>= 1) {
        const float om = __shfl_xor(m, off);
        const int   oi = __shfl_xor(mi, off);
        if (om > m || (om == m && oi < mi)) { m = om; mi = oi; }  // first-index tie-break
    }
    const float e2 = __builtin_amdgcn_exp2f(G - m);
    float ssum = e2;
#pragma unroll
    for (int off = 32; off; off >>= 1) ssum += __shfl_xor(ssum, off);
    out[(size_t)row * kCLS + lane] = e2 / ssum;
    out[(size_t)kB * kCLS + (size_t)row * kCLS + lane] = (lane == mi) ? 1.0f : 0.0f;
}

// ================= Fallback (round-1, known-passing) if ws is too small =================
constexpr int BM = 64, BN = 64, BK = 16;

__global__ __launch_bounds__(256) void gemm_vw(const float* __restrict__ V,
                                               const float* __restrict__ Wm,
                                               const float* __restrict__ cvec,
                                               float* __restrict__ pre) {
    __shared__ float As[BK][BM + 4];
    __shared__ float Bs[BK][BN + 4];
    const int tid = threadIdx.x;
    const int tx = tid & 15, ty = tid >> 4;
    const int m0 = blockIdx.y * BM, n0 = blockIdx.x * BN;
    const int arow = tid >> 2, acol = (tid & 3) << 2;
    const int brow = tid >> 4, bcol = (tid & 15) << 2;
    const float* vptr = V + (size_t)(m0 + arow) * kVIS + acol;
    const float* wptr = Wm + (size_t)brow * kHID + n0 + bcol;
    float acc[4][4] = {};
    for (int k0 = 0; k0 < kVIS; k0 += BK) {
        const float4 a4 = *(const float4*)(vptr + k0);
        const float4 b4 = *(const float4*)(wptr + (size_t)k0 * kHID);
        __syncthreads();
        As[acol + 0][arow] = a4.x; As[acol + 1][arow] = a4.y;
        As[acol + 2][arow] = a4.z; As[acol + 3][arow] = a4.w;
        *(float4*)&Bs[brow][bcol] = b4;
        __syncthreads();
#pragma unroll
        for (int k = 0; k < BK; ++k) {
            const float4 av = *(const float4*)&As[k][ty << 2];
            const float4 bv = *(const float4*)&Bs[k][tx << 2];
            const float a[4] = {av.x, av.y, av.z, av.w};
            const float b[4] = {bv.x, bv.y, bv.z, bv.w};
#pragma unroll
            for (int i = 0; i < 4; ++i)
#pragma unroll
                for (int j = 0; j < 4; ++j) acc[i][j] += a[i] * b[j];
        }
    }
#pragma unroll
    for (int i = 0; i < 4; ++i) {
        const int row = m0 + (ty << 2) + i;
        const int col = n0 + (tx << 2);
        const float4 cv = *(const float4*)(cvec + col);
        float4 o;
        o.x = acc[i][0] + cv.x; o.y = acc[i][1] + cv.y;
        o.z = acc[i][2] + cv.z; o.w = acc[i][3] + cv.w;
        *(float4*)(pre + (size_t)row * kHID + col) = o;
    }
}

__device__ __forceinline__ float softplus_f(float x) {
    return fmaxf(x, 0.f) + __logf(1.f + __expf(-fabsf(x)));
}

__global__ __launch_bounds__(256) void classify(const float* __restrict__ pre,
                                                const float* __restrict__ U,
                                                const float* __restrict__ dvec,
                                                float* __restrict__ out) {
    __shared__ float preS[4][kHID];
    __shared__ float Fs[4][kCLS];
    const int tid = threadIdx.x;
    const int lane = tid & 63, wave = tid >> 6;
    const int b0 = blockIdx.x * 4;
    const float4* src = (const float4*)(pre + (size_t)b0 * kHID);
    float4* dst = (float4*)preS;
    for (int i = tid; i < kHID; i += 256) dst[i] = src[i];
    __syncthreads();
    for (int yi = 0; yi < 16; ++yi) {
        const int y = (wave << 4) + yi;
        const float* Uy = U + (size_t)y * kHID;
        float a0 = 0.f, a1 = 0.f, a2 = 0.f, a3 = 0.f;
#pragma unroll
        for (int it = 0; it < kHID / 64; ++it) {
            const int j = lane + (it << 6);
            const float u = Uy[j];
            a0 += softplus_f(preS[0][j] + u);
            a1 += softplus_f(preS[1][j] + u);
            a2 += softplus_f(preS[2][j] + u);
            a3 += softplus_f(preS[3][j] + u);
        }
        double d0 = a0, d1 = a1, d2 = a2, d3 = a3;
#pragma unroll
        for (int off = 32; off; off >>= 1) {
            d0 += __shfl_xor(d0, off); d1 += __shfl_xor(d1, off);
            d2 += __shfl_xor(d2, off); d3 += __shfl_xor(d3, off);
        }
        if (lane == 0) {
            const float dy = dvec[y];
            Fs[0][y] = (float)d0 + dy; Fs[1][y] = (float)d1 + dy;
            Fs[2][y] = (float)d2 + dy; Fs[3][y] = (float)d3 + dy;
        }
    }
    __syncthreads();
    const float F = Fs[wave][lane];
    float m = F; int mi = lane;
#pragma unroll
    for (int off = 32; off; off >>= 1) {
        const float om = __shfl_xor(m, off);
        const int oi = __shfl_xor(mi, off);
        if (om > m || (om == m && oi < mi)) { m = om; mi = oi; }
    }
    const float e = __expf(F - m);
    float s = e;
#pragma unroll
    for (int off = 32; off; off >>= 1) s += __shfl_xor(s, off);
    const int row = b0 + wave;
    out[(size_t)row * kCLS + lane] = e / s;
    out[(size_t)kB * kCLS + (size_t)row * kCLS + lane] = (lane == mi) ? 1.0f : 0.0f;
}

extern "C" void kernel_launch(void* const* d_in, const int* in_sizes, int n_in,
                              void* d_out, int out_size, void* d_ws, size_t ws_size,
                              hipStream_t stream) {
    const float* v = (const float*)d_in[0];
    const float* W = (const float*)d_in[1];
    const float* c = (const float*)d_in[2];
    const float* d = (const float*)d_in[3];
    const float* U = (const float*)d_in[4];
    float* out = (float*)d_out;
    char* ws = (char*)d_ws;

    // ws layout: vh 8MB | vl 8MB | Wt_h 4MB | Wt_l 4MB | Utp 256KB | Fpart 8MB
    const size_t need = 33816576;
    if (ws_size >= need) {
        unsigned short* vh  = (unsigned short*)(ws);
        unsigned short* vl  = (unsigned short*)(ws + 8388608);
        unsigned short* wth = (unsigned short*)(ws + 16777216);
        unsigned short* wtl = (unsigned short*)(ws + 20971520);
        float* Utp   = (float*)(ws + 25165824);
        float* Fpart = (float*)(ws + 25427968);
        prep_all<<<4864, 256, 0, stream>>>(v, W, U, vh, vl, wth, wtl, Utp);
        gemm_fused<<<512, 512, 0, stream>>>(vh, vl, wth, wtl, c, Utp, Fpart);
        softmax_final<<<kB / 4, 256, 0, stream>>>(Fpart, d, out);
    } else {
        float* pre = (float*)ws;
        gemm_vw<<<dim3(kHID / BN, kB / BM), 256, 0, stream>>>(v, W, c, pre);
        classify<<<kB / 4, 256, 0, stream>>>(pre, U, d, out);
    }
}

// Round 7
// 130.152 us; speedup vs baseline: 1.9376x; 1.0448x over previous
//
#include <hip/hip_runtime.h>

// Problem sizes (fixed by the reference)
constexpr int kB    = 2048;  // batch
constexpr int kVIS  = 2048;  // visible units (GEMM K)
constexpr int kHID  = 1024;  // hidden units (GEMM N)
constexpr int kCLS  = 64;    // classes
constexpr float kLog2e = 1.4426950408889634f;

typedef __attribute__((ext_vector_type(8))) short bf16x8;
typedef __attribute__((ext_vector_type(4))) float f32x4;
typedef __attribute__((ext_vector_type(2))) float f32x2;

typedef __attribute__((address_space(3))) unsigned       as3_u32;
typedef __attribute__((address_space(1))) const unsigned as1_u32;

__device__ __forceinline__ void g2lds16(const void* g, void* l) {
    // async global->LDS DMA, 16 B per lane; LDS dest is wave-base + lane*16
    __builtin_amdgcn_global_load_lds((as1_u32*)g, (as3_u32*)l, 16, 0, 0);
}

__device__ __forceinline__ unsigned short f2bf(float x) {
    unsigned u = __float_as_uint(x);
    u += 0x7fffu + ((u >> 16) & 1u);
    return (unsigned short)(u >> 16);
}
__device__ __forceinline__ float bf2f(unsigned short h) {
    return __uint_as_float(((unsigned)h) << 16);
}

// ---------------- Prep (merged): split v, split+transpose W, pack+scale U ----------------
// R4 version, unchanged (proven).
__global__ __launch_bounds__(256) void prep_all(const float* __restrict__ v,
                                                const float* __restrict__ W,
                                                const float* __restrict__ U,
                                                unsigned short* __restrict__ vh,
                                                unsigned short* __restrict__ vl,
                                                unsigned short* __restrict__ wth,
                                                unsigned short* __restrict__ wtl,
                                                float* __restrict__ Utp) {
    __shared__ float T[64][65];
    const int bx = blockIdx.x;
    if (bx < 4096) {
        const int i = (bx * 256 + threadIdx.x) * 4;
        const float4 xv = *(const float4*)(v + i);
        ushort4 h, l;
        h.x = f2bf(xv.x); l.x = f2bf(xv.x - bf2f(h.x));
        h.y = f2bf(xv.y); l.y = f2bf(xv.y - bf2f(h.y));
        h.z = f2bf(xv.z); l.z = f2bf(xv.z - bf2f(h.z));
        h.w = f2bf(xv.w); l.w = f2bf(xv.w - bf2f(h.w));
        *(ushort4*)(vh + i) = h;
        *(ushort4*)(vl + i) = l;
    } else if (bx < 4608) {
        const int b = bx - 4096;                 // 0..511
        const int n0 = (b & 15) * 64;            // 16 n-tiles
        const int k0 = (b >> 4) * 64;            // 32 k-tiles
        const int c = threadIdx.x & 63, r0 = threadIdx.x >> 6;  // lane, wave
#pragma unroll
        for (int ps = 0; ps < 16; ++ps) {
            const int r = r0 + ps * 4;           // tile row (k)
            T[r][c] = W[(size_t)(k0 + r) * kHID + n0 + c];   // 256 B/wave, coalesced
        }
        __syncthreads();
#pragma unroll
        for (int ps = 0; ps < 16; ++ps) {
            const int nn = r0 + ps * 4;          // tile row (n) of output
            const float x = T[c][nn];            // 2-way bank alias
            const unsigned short h = f2bf(x);
            const unsigned short l = f2bf(x - bf2f(h));
            const size_t o = (size_t)(n0 + nn) * kVIS + k0 + c;
            wth[o] = h;                          // 128 B/wave, coalesced
            wtl[o] = l;
        }
    } else {
        const int id = (bx - 4608) * 256 + threadIdx.x;  // 0..65535
        const int j = id >> 6, y = id & 63;
        Utp[(((j >> 2) * kCLS + y) << 2) + (j & 3)] = U[(size_t)y * kHID + j] * kLog2e;
    }
}

// ---------------- Fused kernel: split-bf16 MFMA GEMM + softplus partial-F epilogue ------
// R17: 1024-thread block, 128x64 tile, 3-buffer K=64 counted-vmcnt pipeline.
// Lesson stack: R0 (2-buf, 1 barrier/slab) = 51.3 us, sync-bound — with 2 buffers a
// counted vmcnt is IMPOSSIBLE (only 1 slab can be in flight; the wait must drain it).
// R16 (4-buf K=32 + parity split) = 60 us — pipeline depth was right, but only half
// the waves had work per barrier interval and barrier count doubled. R17 fixes both:
// 16 waves = 4mh x 2nh x 2kh, EVERY wave computes EVERY K=64 slab with R0's exact
// per-wave economics (32x32 quadrant, 8 frag ds_read_b128, 12 MFMA). Slab = 48 KB
// (A 128rx64k h+l 32 KB, B 64rx64k h+l 16 KB); 3 buffers = 144 KB <= 160 -> 1 block/CU,
// grid 256 = 1/CU. Loop: vmcnt(3) [slab t landed; slab t+1's 3 DMAs stay in flight
// ACROSS the barrier] -> s_barrier -> compute(t) -> s_barrier -> issue(t+2) into the
// buffer last read at t-1. Latency budget per slab = one full iteration >> HBM latency.
// Race safety: issue(t+2) writes buf (t-1)%3; every wave's compute(t-1) finished before
// its bottom-barrier(t-1) <= my bottom-barrier(t) < my issue(t+2). compute(t) reads all
// waves' slab-t data: each wave passed its own vmcnt(3) before top-barrier(t).
// sched_barrier(0) after each raw s_barrier: raw barrier is NOT a compiler memory fence
// and the DMA writes are invisible to alias analysis (rule #18 / m104).
__global__ __launch_bounds__(1024, 1) void gemm_fused(const unsigned short* __restrict__ vh,
                                                      const unsigned short* __restrict__ vl,
                                                      const unsigned short* __restrict__ wth,
                                                      const unsigned short* __restrict__ wtl,
                                                      const float* __restrict__ cvec,
                                                      const float* __restrict__ Utp,
                                                      float* __restrict__ Fpart) {
    constexpr int kSlabElems = 24576;   // 48 KB: A-h[0,8192) A-l[8192,16384) B-h/l[16384,24576)
    __shared__ __align__(16) union SMem {
        unsigned short stage[3][kSlabElems];  // 147456 B
        float psH[2][128][68];                // 69632 B, overlays stage
    } smem;

    const int tid = threadIdx.x;
    const int lane = tid & 63, wave = tid >> 6;   // wave 0..15
    const int mh = wave >> 2;                     // m-quarter: rows mh*32..+32 (of 128)
    const int nh = (wave >> 1) & 1;               // n-half: cols nh*32..+32
    const int kh = wave & 1;                      // k-half: k in [kh*32,+32) of each slab

    // grid: 256 blocks = 16 mstripes x 16 ncols; XCD x owns ncols {2x, 2x+1} (B-panel
    // locality per XCD-L2); bijective.
    const int bid = blockIdx.x;
    const int x = bid & 7, s = bid >> 3;          // s: 0..31
    const int ncol = (x << 1) | (s & 1);          // 0..15
    const int mstripe = s >> 1;                   // 0..15
    const int m0 = mstripe << 7, n0 = ncol << 6;

    // staging map (per thread, 3 DMA/slab): A-h slot tid, A-l slot tid, B slot tid
    // (tid<512 -> B-h rows, tid>=512 -> B-l rows). XOR octet swizzle on the SOURCE
    // (octet q^(row&7)), linear LDS dest (m173 pattern) — same scheme as R0.
    const int rA = tid >> 3, qA = tid & 7;
    const int octA = (qA ^ (rA & 7)) << 3;
    const unsigned short* const srcAh = vh + (size_t)(m0 + rA) * kVIS + octA;
    const unsigned short* const srcAl = vl + (size_t)(m0 + rA) * kVIS + octA;
    const int tb = tid & 511;
    const int rB = tb >> 3, qB = tb & 7;
    const int octB = (qB ^ (rB & 7)) << 3;
    const unsigned short* const srcB =
        ((tid < 512) ? wth : wtl) + (size_t)(n0 + rB) * kVIS + octB;
    const int dOff = tid << 3;                    // elems; 16 B per thread, wave-linear

    unsigned short* const st = &smem.stage[0][0];

    // fragment addressing: row R at R*64 elems within its plane; logical octet
    // (kh*4+fq) lives at position (kh*4+fq)^(R&7); R&7 == fm&7 (bases mult of 32).
    const int fm = lane & 15, fq = lane >> 4;
    const int p = (((kh << 2) + fq) ^ (fm & 7)) << 3;
    const int ar0 = ((mh * 32 + fm) << 6) + p;        // A-h; A-l at +8192
    const int ar1 = ar0 + (16 << 6);
    const int br0 = 16384 + ((nh * 32 + fm) << 6) + p; // B-h; B-l at +4096
    const int br1 = br0 + (16 << 6);

    f32x4 acc[2][2] = {};   // [m-tile][n-tile], 16 VGPRs

    auto stage_slab = [&](int slab, unsigned short* buf) {
        const int koff = slab << 6;
        g2lds16(srcAh + koff, buf + dOff);
        g2lds16(srcAl + koff, buf + 8192 + dOff);
        g2lds16(srcB + koff, buf + 16384 + dOff);
    };
    auto compute = [&](const unsigned short* buf) {
        const bf16x8 a_h0 = *(const bf16x8*)(buf + ar0);
        const bf16x8 a_h1 = *(const bf16x8*)(buf + ar1);
        const bf16x8 a_l0 = *(const bf16x8*)(buf + 8192 + ar0);
        const bf16x8 a_l1 = *(const bf16x8*)(buf + 8192 + ar1);
        const bf16x8 b_h0 = *(const bf16x8*)(buf + br0);
        const bf16x8 b_h1 = *(const bf16x8*)(buf + br1);
        const bf16x8 b_l0 = *(const bf16x8*)(buf + 4096 + br0);
        const bf16x8 b_l1 = *(const bf16x8*)(buf + 4096 + br1);
        acc[0][0] = __builtin_amdgcn_mfma_f32_16x16x32_bf16(a_h0, b_h0, acc[0][0], 0, 0, 0);
        acc[0][0] = __builtin_amdgcn_mfma_f32_16x16x32_bf16(a_h0, b_l0, acc[0][0], 0, 0, 0);
        acc[0][0] = __builtin_amdgcn_mfma_f32_16x16x32_bf16(a_l0, b_h0, acc[0][0], 0, 0, 0);
        acc[0][1] = __builtin_amdgcn_mfma_f32_16x16x32_bf16(a_h0, b_h1, acc[0][1], 0, 0, 0);
        acc[0][1] = __builtin_amdgcn_mfma_f32_16x16x32_bf16(a_h0, b_l1, acc[0][1], 0, 0, 0);
        acc[0][1] = __builtin_amdgcn_mfma_f32_16x16x32_bf16(a_l0, b_h1, acc[0][1], 0, 0, 0);
        acc[1][0] = __builtin_amdgcn_mfma_f32_16x16x32_bf16(a_h1, b_h0, acc[1][0], 0, 0, 0);
        acc[1][0] = __builtin_amdgcn_mfma_f32_16x16x32_bf16(a_h1, b_l0, acc[1][0], 0, 0, 0);
        acc[1][0] = __builtin_amdgcn_mfma_f32_16x16x32_bf16(a_l1, b_h0, acc[1][0], 0, 0, 0);
        acc[1][1] = __builtin_amdgcn_mfma_f32_16x16x32_bf16(a_h1, b_h1, acc[1][1], 0, 0, 0);
        acc[1][1] = __builtin_amdgcn_mfma_f32_16x16x32_bf16(a_h1, b_l1, acc[1][1], 0, 0, 0);
        acc[1][1] = __builtin_amdgcn_mfma_f32_16x16x32_bf16(a_l1, b_h1, acc[1][1], 0, 0, 0);
    };

    // prologue: slabs 0 and 1 in flight (6 DMAs/thread)
    stage_slab(0, st);
    stage_slab(1, st + kSlabElems);

    unsigned short* bufPrev = st + 2 * kSlabElems;  // receives slab t+2 ((t+2)%3==(t-1)%3)
    unsigned short* bufCur  = st;                   // slab t%3
    unsigned short* bufNext = st + kSlabElems;      // slab (t+1)%3

    for (int t = 0; t < 31; ++t) {
        // outstanding: slab t (3, maybe landed) + slab t+1 (3) -> vmcnt(3) waits slab t
        asm volatile("s_waitcnt vmcnt(3)" ::: "memory");
        __builtin_amdgcn_s_barrier();            // everyone's slab-t landed
        __builtin_amdgcn_sched_barrier(0);
        compute(bufCur);
        __builtin_amdgcn_s_barrier();            // all reads of bufCur consumed (lgkm'd by MFMA deps)
        __builtin_amdgcn_sched_barrier(0);
        if (t < 30) stage_slab(t + 2, bufPrev);  // overwrite slab t-1's buffer
        unsigned short* tmp = bufPrev; bufPrev = bufCur; bufCur = bufNext; bufNext = tmp;
    }
    // peeled t=31: only slab 31's 3 DMAs outstanding
    asm volatile("s_waitcnt vmcnt(0)" ::: "memory");
    __builtin_amdgcn_s_barrier();
    __builtin_amdgcn_sched_barrier(0);
    compute(bufCur);
    __syncthreads();   // all stage reads retired before psH overlays it

    // ---- epilogue phase 1: k-half partials -> psH[kh] (log2 domain; c added once, kh=0)
    // for fixed kh, the 8 (mh,nh) waves tile the full 128x64 -> no overlap
#pragma unroll
    for (int j = 0; j < 2; ++j) {
        const int col = nh * 32 + j * 16 + fm;         // local hid col 0..63
        const float cadd = kh ? 0.f : cvec[n0 + col];
#pragma unroll
        for (int i = 0; i < 2; ++i) {
            const int rbase = mh * 32 + i * 16 + fq * 4;  // local row 0..127
#pragma unroll
            for (int rr = 0; rr < 4; ++rr)
                smem.psH[kh][rbase + rr][col] = (acc[i][j][rr] + cadd) * kLog2e;
        }
    }
    __syncthreads();

    // ---- merge k-half planes once (psH[0] += psH[1]); 2048 float4, 2/thread
#pragma unroll
    for (int s2 = 0; s2 < 2; ++s2) {
        const int id = tid + (s2 << 10);               // 0..2047
        const int row = id >> 4, q = id & 15;
        float4* d = (float4*)&smem.psH[0][row][q << 2];
        const float4* a = (const float4*)&smem.psH[1][row][q << 2];
        const float4 va = *a, vd = *d;
        *d = make_float4(vd.x + va.x, vd.y + va.y, vd.z + va.z, vd.w + va.w);
    }
    __syncthreads();

    // ---- epilogue phase 2: packed-f32 softplus; wave owns rows [wave*8,+8), lane=class
    const int q0 = (n0 >> 2);
    f32x2 relu2[8], prod2[8];
#pragma unroll
    for (int rr = 0; rr < 8; ++rr) { relu2[rr] = (f32x2)(0.f); prod2[rr] = (f32x2)(1.f); }

    const f32x2 zero2 = (f32x2)(0.f);
    for (int jc = 0; jc < 64; jc += 8) {
        const float4 ua = ((const float4*)Utp)[(q0 + (jc >> 2) + 0) * kCLS + lane];
        const float4 ub = ((const float4*)Utp)[(q0 + (jc >> 2) + 1) * kCLS + lane];
        const f32x2 u01 = {ua.x, ua.y}, u23 = {ua.z, ua.w};
        const f32x2 u45 = {ub.x, ub.y}, u67 = {ub.z, ub.w};
#pragma unroll
        for (int rr = 0; rr < 8; ++rr) {
            const int row = wave * 8 + rr;
            const float4 p0 = *(const float4*)&smem.psH[0][row][jc];      // broadcast
            const float4 p1 = *(const float4*)&smem.psH[0][row][jc + 4];  // broadcast
            f32x2 tp[4];
            tp[0] = (f32x2){p0.x, p0.y} + u01;
            tp[1] = (f32x2){p0.z, p0.w} + u23;
            tp[2] = (f32x2){p1.x, p1.y} + u45;
            tp[3] = (f32x2){p1.z, p1.w} + u67;
#pragma unroll
            for (int g = 0; g < 4; ++g) {
                const f32x2 t = tp[g];
                f32x2 e;
                e.x = __builtin_amdgcn_exp2f(-__builtin_fabsf(t.x));
                e.y = __builtin_amdgcn_exp2f(-__builtin_fabsf(t.y));
                prod2[rr] = __builtin_elementwise_fma(prod2[rr], e, prod2[rr]);  // *= (1+e)
                relu2[rr] += __builtin_elementwise_max(t, zero2);
            }
        }
    }
#pragma unroll
    for (int rr = 0; rr < 8; ++rr) {
        const float contrib = relu2[rr].x + relu2[rr].y +
                              __builtin_amdgcn_logf(prod2[rr].x * prod2[rr].y);  // log2 domain
        Fpart[((size_t)ncol * kB + m0 + wave * 8 + rr) * kCLS + lane] = contrib;
    }
}

// ---------------- Final: sum 16 partials (double), softmax, argmax, one-hot ------------
__global__ __launch_bounds__(256) void softmax_final(const float* __restrict__ Fpart,
                                                     const float* __restrict__ dvec,
                                                     float* __restrict__ out) {
    const int tid = threadIdx.x;
    const int lane = tid & 63, wave = tid >> 6;
    const int row = blockIdx.x * 4 + wave;
    double s = 0.0;
#pragma unroll
    for (int k = 0; k < kHID / 64; ++k)
        s += (double)Fpart[((size_t)k * kB + row) * kCLS + lane];
    const float G = (float)s + dvec[lane] * kLog2e;  // log2-domain logit

    float m = G;
    int mi = lane;
#pragma unroll
    for (int off = 32; off; off >>= 1) {
        const float om = __shfl_xor(m, off);
        const int   oi = __shfl_xor(mi, off);
        if (om > m || (om == m && oi < mi)) { m = om; mi = oi; }  // first-index tie-break
    }
    const float e2 = __builtin_amdgcn_exp2f(G - m);
    float ssum = e2;
#pragma unroll
    for (int off = 32; off; off >>= 1) ssum += __shfl_xor(ssum, off);
    out[(size_t)row * kCLS + lane] = e2 / ssum;
    out[(size_t)kB * kCLS + (size_t)row * kCLS + lane] = (lane == mi) ? 1.0f : 0.0f;
}

// ================= Fallback (round-1, known-passing) if ws is too small =================
constexpr int BM = 64, BN = 64, BK = 16;

__global__ __launch_bounds__(256) void gemm_vw(const float* __restrict__ V,
                                               const float* __restrict__ Wm,
                                               const float* __restrict__ cvec,
                                               float* __restrict__ pre) {
    __shared__ float As[BK][BM + 4];
    __shared__ float Bs[BK][BN + 4];
    const int tid = threadIdx.x;
    const int tx = tid & 15, ty = tid >> 4;
    const int m0 = blockIdx.y * BM, n0 = blockIdx.x * BN;
    const int arow = tid >> 2, acol = (tid & 3) << 2;
    const int brow = tid >> 4, bcol = (tid & 15) << 2;
    const float* vptr = V + (size_t)(m0 + arow) * kVIS + acol;
    const float* wptr = Wm + (size_t)brow * kHID + n0 + bcol;
    float acc[4][4] = {};
    for (int k0 = 0; k0 < kVIS; k0 += BK) {
        const float4 a4 = *(const float4*)(vptr + k0);
        const float4 b4 = *(const float4*)(wptr + (size_t)k0 * kHID);
        __syncthreads();
        As[acol + 0][arow] = a4.x; As[acol + 1][arow] = a4.y;
        As[acol + 2][arow] = a4.z; As[acol + 3][arow] = a4.w;
        *(float4*)&Bs[brow][bcol] = b4;
        __syncthreads();
#pragma unroll
        for (int k = 0; k < BK; ++k) {
            const float4 av = *(const float4*)&As[k][ty << 2];
            const float4 bv = *(const float4*)&Bs[k][tx << 2];
            const float a[4] = {av.x, av.y, av.z, av.w};
            const float b[4] = {bv.x, bv.y, bv.z, bv.w};
#pragma unroll
            for (int i = 0; i < 4; ++i)
#pragma unroll
                for (int j = 0; j < 4; ++j) acc[i][j] += a[i] * b[j];
        }
    }
#pragma unroll
    for (int i = 0; i < 4; ++i) {
        const int row = m0 + (ty << 2) + i;
        const int col = n0 + (tx << 2);
        const float4 cv = *(const float4*)(cvec + col);
        float4 o;
        o.x = acc[i][0] + cv.x; o.y = acc[i][1] + cv.y;
        o.z = acc[i][2] + cv.z; o.w = acc[i][3] + cv.w;
        *(float4*)(pre + (size_t)row * kHID + col) = o;
    }
}

__device__ __forceinline__ float softplus_f(float x) {
    return fmaxf(x, 0.f) + __logf(1.f + __expf(-fabsf(x)));
}

__global__ __launch_bounds__(256) void classify(const float* __restrict__ pre,
                                                const float* __restrict__ U,
                                                const float* __restrict__ dvec,
                                                float* __restrict__ out) {
    __shared__ float preS[4][kHID];
    __shared__ float Fs[4][kCLS];
    const int tid = threadIdx.x;
    const int lane = tid & 63, wave = tid >> 6;
    const int b0 = blockIdx.x * 4;
    const float4* src = (const float4*)(pre + (size_t)b0 * kHID);
    float4* dst = (float4*)preS;
    for (int i = tid; i < kHID; i += 256) dst[i] = src[i];
    __syncthreads();
    for (int yi = 0; yi < 16; ++yi) {
        const int y = (wave << 4) + yi;
        const float* Uy = U + (size_t)y * kHID;
        float a0 = 0.f, a1 = 0.f, a2 = 0.f, a3 = 0.f;
#pragma unroll
        for (int it = 0; it < kHID / 64; ++it) {
            const int j = lane + (it << 6);
            const float u = Uy[j];
            a0 += softplus_f(preS[0][j] + u);
            a1 += softplus_f(preS[1][j] + u);
            a2 += softplus_f(preS[2][j] + u);
            a3 += softplus_f(preS[3][j] + u);
        }
        double d0 = a0, d1 = a1, d2 = a2, d3 = a3;
#pragma unroll
        for (int off = 32; off; off >>= 1) {
            d0 += __shfl_xor(d0, off); d1 += __shfl_xor(d1, off);
            d2 += __shfl_xor(d2, off); d3 += __shfl_xor(d3, off);
        }
        if (lane == 0) {
            const float dy = dvec[y];
            Fs[0][y] = (float)d0 + dy; Fs[1][y] = (float)d1 + dy;
            Fs[2][y] = (float)d2 + dy; Fs[3][y] = (float)d3 + dy;
        }
    }
    __syncthreads();
    const float F = Fs[wave][lane];
    float m = F; int mi = lane;
#pragma unroll
    for (int off = 32; off; off >>= 1) {
        const float om = __shfl_xor(m, off);
        const int oi = __shfl_xor(mi, off);
        if (om > m || (om == m && oi < mi)) { m = om; mi = oi; }
    }
    const float e = __expf(F - m);
    float s = e;
#pragma unroll
    for (int off = 32; off; off >>= 1) s += __shfl_xor(s, off);
    const int row = b0 + wave;
    out[(size_t)row * kCLS + lane] = e / s;
    out[(size_t)kB * kCLS + (size_t)row * kCLS + lane] = (lane == mi) ? 1.0f : 0.0f;
}

extern "C" void kernel_launch(void* const* d_in, const int* in_sizes, int n_in,
                              void* d_out, int out_size, void* d_ws, size_t ws_size,
                              hipStream_t stream) {
    const float* v = (const float*)d_in[0];
    const float* W = (const float*)d_in[1];
    const float* c = (const float*)d_in[2];
    const float* d = (const float*)d_in[3];
    const float* U = (const float*)d_in[4];
    float* out = (float*)d_out;
    char* ws = (char*)d_ws;

    // ws layout: vh 8MB | vl 8MB | Wt_h 4MB | Wt_l 4MB | Utp 256KB | Fpart 8MB
    const size_t need = 33816576;
    if (ws_size >= need) {
        unsigned short* vh  = (unsigned short*)(ws);
        unsigned short* vl  = (unsigned short*)(ws + 8388608);
        unsigned short* wth = (unsigned short*)(ws + 16777216);
        unsigned short* wtl = (unsigned short*)(ws + 20971520);
        float* Utp   = (float*)(ws + 25165824);
        float* Fpart = (float*)(ws + 25427968);
        prep_all<<<4864, 256, 0, stream>>>(v, W, U, vh, vl, wth, wtl, Utp);
        gemm_fused<<<256, 1024, 0, stream>>>(vh, vl, wth, wtl, c, Utp, Fpart);
        softmax_final<<<kB / 4, 256, 0, stream>>>(Fpart, d, out);
    } else {
        float* pre = (float*)ws;
        gemm_vw<<<dim3(kHID / BN, kB / BM), 256, 0, stream>>>(v, W, c, pre);
        classify<<<kB / 4, 256, 0, stream>>>(pre, U, d, out);
    }
}